// Round 1
// baseline (1209.655 us; speedup 1.0000x reference)
//
#include <hip/hip_runtime.h>
#include <math.h>

#define N_NODES 50000
#define N_EDGES 800000
#define N_GRAPHS 512
#define SLOPE 0.2f
static constexpr float EPS_BN = 1e-5f;

// ---------------- CSR build ----------------

__global__ void hist_kernel(const int* __restrict__ dst, int* __restrict__ cnt) {
    int e = blockIdx.x * blockDim.x + threadIdx.x;
    if (e < N_EDGES) atomicAdd(&cnt[dst[e]], 1);
}

// per-1024 block inclusive scan; writes row_ptr[n+1] = local inclusive, blk[b] = block total
__global__ void scan1_kernel(const int* __restrict__ cnt, int* __restrict__ row_ptr,
                             int* __restrict__ blk) {
    __shared__ int tmp[1024];
    int t = threadIdx.x;
    int n = blockIdx.x * 1024 + t;
    int v = (n < N_NODES) ? cnt[n] : 0;
    tmp[t] = v;
    __syncthreads();
    for (int off = 1; off < 1024; off <<= 1) {
        int x = (t >= off) ? tmp[t - off] : 0;
        __syncthreads();
        tmp[t] += x;
        __syncthreads();
    }
    if (n < N_NODES) row_ptr[n + 1] = tmp[t];
    if (t == 1023) blk[blockIdx.x] = tmp[t];
}

__global__ void scan2_kernel(int* __restrict__ blk, int nb) {
    if (blockIdx.x == 0 && threadIdx.x == 0) {
        int run = 0;
        for (int i = 0; i < nb; i++) { int t = blk[i]; blk[i] = run; run += t; }
    }
}

__global__ void scan3_kernel(int* __restrict__ row_ptr, const int* __restrict__ blk) {
    int n = blockIdx.x * blockDim.x + threadIdx.x;
    if (n < N_NODES) row_ptr[n + 1] += blk[n >> 10];
    if (n == 0) row_ptr[0] = 0;
}

__global__ void fillcopy_kernel(const int* __restrict__ row_ptr, int* __restrict__ fill) {
    int n = blockIdx.x * blockDim.x + threadIdx.x;
    if (n < N_NODES) fill[n] = row_ptr[n];
}

__global__ void scatter_kernel(const int* __restrict__ dst, int* __restrict__ fill,
                               int* __restrict__ perm) {
    int e = blockIdx.x * blockDim.x + threadIdx.x;
    if (e < N_EDGES) {
        int pos = atomicAdd(&fill[dst[e]], 1);
        perm[pos] = e;
    }
}

// ---------------- node transform: xl = h@Wl+bl, xr = h@Wr+br ----------------

template <int K>
__global__ __launch_bounds__(256) void transform_kernel(
    const float* __restrict__ h,
    const float* __restrict__ Wl, const float* __restrict__ bl,
    const float* __restrict__ Wr, const float* __restrict__ br,
    float* __restrict__ xl, float* __restrict__ xr) {
    __shared__ float sWl[K * 64];
    __shared__ float sWr[K * 64];
    __shared__ float sbl[64], sbr[64];
    __shared__ float sh[4][K];
    int t = threadIdx.x;
    for (int i = t; i < K * 64; i += 256) { sWl[i] = Wl[i]; sWr[i] = Wr[i]; }
    if (t < 64) { sbl[t] = bl[t]; sbr[t] = br[t]; }
    int nl = t >> 6;
    int k = t & 63;
    int n = blockIdx.x * 4 + nl;   // grid is exact: 50000 = 12500*4
    if (k < K) sh[nl][k] = h[n * K + k];
    __syncthreads();
    float al = sbl[k], ar = sbr[k];
#pragma unroll
    for (int j = 0; j < K; j++) {
        float hv = sh[nl][j];
        al = fmaf(hv, sWl[j * 64 + k], al);
        ar = fmaf(hv, sWr[j * 64 + k], ar);
    }
    xl[n * 64 + k] = al;
    xr[n * 64 + k] = ar;
}

// ---------------- GATv2 layer: one wave (64 lanes) per node, online softmax ----------------

__global__ __launch_bounds__(256) void gat_kernel(
    const float* __restrict__ xl, const float* __restrict__ xr,
    const float* __restrict__ ea,
    const int* __restrict__ src,
    const int* __restrict__ perm, const int* __restrict__ row_ptr,
    const float* __restrict__ We, const float* __restrict__ att,
    const float* __restrict__ bo,
    const float* __restrict__ bn_g, const float* __restrict__ bn_b,
    const float* __restrict__ bn_m, const float* __restrict__ bn_v,
    float* __restrict__ hout) {
    int t = threadIdx.x;
    int nl = t >> 6;
    int k = t & 63;
    int n = blockIdx.x * 4 + nl;   // grid exact

    float we0 = We[k], we1 = We[64 + k], we2 = We[128 + k];
    float ak = att[k];
    float xrk = xr[n * 64 + k];
    int beg = row_ptr[n], end = row_ptr[n + 1];

    float mrun = -INFINITY, z = 0.f, o = 0.f;
    for (int idx = beg; idx < end; ++idx) {
        int e = perm[idx];
        int s = src[e];
        float xls = xl[s * 64 + k];
        float e0 = ea[e * 3 + 0], e1 = ea[e * 3 + 1], e2 = ea[e * 3 + 2];
        float tt = xls + xrk + e0 * we0 + e1 * we1 + e2 * we2;
        tt = (tt > 0.f) ? tt : SLOPE * tt;
        float lv = ak * tt;
        // full-wave (64-lane) butterfly sum -> every lane holds the logit
        for (int off = 32; off > 0; off >>= 1) lv += __shfl_xor(lv, off, 64);
        float mn = fmaxf(mrun, lv);
        float sc = expf(mrun - mn);   // first iter: expf(-inf)=0
        float p = expf(lv - mn);
        z = z * sc + p;
        o = o * sc + p * xls;
        mrun = mn;
    }
    float outv = o / fmaxf(z, 1e-16f) + bo[k];
    // BN (eval) + ReLU fused
    float inv = 1.0f / sqrtf(bn_v[k] + EPS_BN);
    float hn = (outv - bn_m[k]) * (bn_g[k] * inv) + bn_b[k];
    hout[n * 64 + k] = fmaxf(hn, 0.f);
}

// ---------------- readout ----------------

__global__ void bounds_kernel(const int* __restrict__ batch, int* __restrict__ gstart) {
    int g = blockIdx.x * blockDim.x + threadIdx.x;
    if (g > N_GRAPHS) return;
    int lo = 0, hi = N_NODES;
    while (lo < hi) {
        int mid = (lo + hi) >> 1;
        if (batch[mid] < g) lo = mid + 1; else hi = mid;
    }
    gstart[g] = lo;
}

__global__ void wcomb_kernel(const float* __restrict__ Wjk, const float* __restrict__ bjk,
                             const float* __restrict__ Whead, const float* __restrict__ bhead,
                             float* __restrict__ wcomb, float* __restrict__ bcomb) {
    int k = threadIdx.x;
    if (k < 64) {
        float s = 0.f;
        for (int j = 0; j < 64; j++) s += Wjk[k * 64 + j] * Whead[j];
        wcomb[k] = s;
    }
    if (k == 0) {
        float s = 0.f;
        for (int j = 0; j < 64; j++) s += bjk[j] * Whead[j];
        *bcomb = s + bhead[0];
    }
}

__global__ __launch_bounds__(64) void pool_kernel(
    const float* __restrict__ h, const int* __restrict__ gstart,
    const float* __restrict__ wcomb, const float* __restrict__ bcomb,
    float* __restrict__ out) {
    int g = blockIdx.x;
    int k = threadIdx.x;
    int s = gstart[g], e = gstart[g + 1];
    float acc = 0.f;
    for (int n = s; n < e; ++n) acc += h[n * 64 + k];
    float cnt = (float)(e - s);
    acc /= fmaxf(cnt, 1.0f);
    float v = acc * wcomb[k];
    for (int off = 32; off > 0; off >>= 1) v += __shfl_xor(v, off, 64);
    if (k == 0) out[g] = v + *bcomb;
}

// ---------------- launch ----------------

extern "C" void kernel_launch(void* const* d_in, const int* in_sizes, int n_in,
                              void* d_out, int out_size, void* d_ws, size_t ws_size,
                              hipStream_t stream) {
    const float* x     = (const float*)d_in[0];
    const float* ea    = (const float*)d_in[1];
    const float* Wl0   = (const float*)d_in[2];
    const float* Wr0   = (const float*)d_in[3];
    const float* bl0   = (const float*)d_in[4];
    const float* br0   = (const float*)d_in[5];
    const float* We0   = (const float*)d_in[6];
    const float* att0  = (const float*)d_in[7];
    const float* bo0   = (const float*)d_in[8];
    const float* Wl    = (const float*)d_in[9];
    const float* Wr    = (const float*)d_in[10];
    const float* bl    = (const float*)d_in[11];
    const float* br    = (const float*)d_in[12];
    const float* We    = (const float*)d_in[13];
    const float* att   = (const float*)d_in[14];
    const float* bo    = (const float*)d_in[15];
    const float* bn_g  = (const float*)d_in[16];
    const float* bn_b  = (const float*)d_in[17];
    const float* bn_m  = (const float*)d_in[18];
    const float* bn_v  = (const float*)d_in[19];
    const float* Wjk   = (const float*)d_in[20];
    const float* bjk   = (const float*)d_in[21];
    const float* Whead = (const float*)d_in[22];
    const float* bhead = (const float*)d_in[23];
    const int* edge_index = (const int*)d_in[24];
    const int* batch      = (const int*)d_in[25];

    const int* srcIdx = edge_index;            // edge_index[0]
    const int* dstIdx = edge_index + N_EDGES;  // edge_index[1]

    char* ws = (char*)d_ws;
    size_t off = 0;
    auto alloc = [&](size_t bytes) -> void* {
        void* p = ws + off;
        off += (bytes + 255) & ~(size_t)255;
        return p;
    };
    float* hA      = (float*)alloc((size_t)N_NODES * 64 * 4);
    float* hB      = (float*)alloc((size_t)N_NODES * 64 * 4);
    float* xlb     = (float*)alloc((size_t)N_NODES * 64 * 4);
    float* xrb     = (float*)alloc((size_t)N_NODES * 64 * 4);
    int*   row_ptr = (int*)alloc((size_t)(N_NODES + 1) * 4);
    int*   fill    = (int*)alloc((size_t)N_NODES * 4);
    int*   blk     = (int*)alloc(64 * 4);
    int*   perm    = (int*)alloc((size_t)N_EDGES * 4);
    int*   gstart  = (int*)alloc((size_t)(N_GRAPHS + 1) * 4);
    float* wcomb   = (float*)alloc(64 * 4);
    float* bcomb   = (float*)alloc(4);

    // ---- CSR build (sort edges by dst) ----
    hipMemsetAsync(fill, 0, (size_t)N_NODES * 4, stream);
    hist_kernel<<<(N_EDGES + 255) / 256, 256, 0, stream>>>(dstIdx, fill);
    const int SCB = (N_NODES + 1023) / 1024;  // 49
    scan1_kernel<<<SCB, 1024, 0, stream>>>(fill, row_ptr, blk);
    scan2_kernel<<<1, 1, 0, stream>>>(blk, SCB);
    scan3_kernel<<<(N_NODES + 255) / 256, 256, 0, stream>>>(row_ptr, blk);
    fillcopy_kernel<<<(N_NODES + 255) / 256, 256, 0, stream>>>(row_ptr, fill);
    scatter_kernel<<<(N_EDGES + 255) / 256, 256, 0, stream>>>(dstIdx, fill, perm);

    const int NB = N_NODES / 4;  // 12500, exact

    // ---- layer 0 (input dim 9) ----
    transform_kernel<9><<<NB, 256, 0, stream>>>(x, Wl0, bl0, Wr0, br0, xlb, xrb);
    gat_kernel<<<NB, 256, 0, stream>>>(xlb, xrb, ea, srcIdx, perm, row_ptr,
                                       We0, att0, bo0,
                                       bn_g, bn_b, bn_m, bn_v, hA);

    // ---- layers 1..4 ----
    float* hcur = hA;
    float* hnext = hB;
    for (int i = 0; i < 4; i++) {
        transform_kernel<64><<<NB, 256, 0, stream>>>(hcur,
                                                     Wl + (size_t)i * 64 * 64, bl + (size_t)i * 64,
                                                     Wr + (size_t)i * 64 * 64, br + (size_t)i * 64,
                                                     xlb, xrb);
        gat_kernel<<<NB, 256, 0, stream>>>(xlb, xrb, ea, srcIdx, perm, row_ptr,
                                           We + (size_t)i * 3 * 64, att + (size_t)i * 64,
                                           bo + (size_t)i * 64,
                                           bn_g + (size_t)(i + 1) * 64, bn_b + (size_t)(i + 1) * 64,
                                           bn_m + (size_t)(i + 1) * 64, bn_v + (size_t)(i + 1) * 64,
                                           hnext);
        float* t = hcur; hcur = hnext; hnext = t;
    }

    // ---- readout: mean-pool then (Wjk@Whead)-folded dot ----
    bounds_kernel<<<3, 256, 0, stream>>>(batch, gstart);
    wcomb_kernel<<<1, 64, 0, stream>>>(Wjk, bjk, Whead, bhead, wcomb, bcomb);
    pool_kernel<<<N_GRAPHS, 64, 0, stream>>>(hcur, gstart, wcomb, bcomb, (float*)d_out);
}

// Round 2
// 867.214 us; speedup vs baseline: 1.3949x; 1.3949x over previous
//
#include <hip/hip_runtime.h>
#include <math.h>

#define N_NODES 50000
#define N_EDGES 800000
#define N_GRAPHS 512
#define SLOPE 0.2f
static constexpr float EPS_BN = 1e-5f;

// ---------------- CSR build ----------------

__global__ void hist_kernel(const int* __restrict__ dst, int* __restrict__ cnt) {
    int e = blockIdx.x * blockDim.x + threadIdx.x;
    if (e < N_EDGES) atomicAdd(&cnt[dst[e]], 1);
}

__global__ void scan1_kernel(const int* __restrict__ cnt, int* __restrict__ row_ptr,
                             int* __restrict__ blk) {
    __shared__ int tmp[1024];
    int t = threadIdx.x;
    int n = blockIdx.x * 1024 + t;
    int v = (n < N_NODES) ? cnt[n] : 0;
    tmp[t] = v;
    __syncthreads();
    for (int off = 1; off < 1024; off <<= 1) {
        int x = (t >= off) ? tmp[t - off] : 0;
        __syncthreads();
        tmp[t] += x;
        __syncthreads();
    }
    if (n < N_NODES) row_ptr[n + 1] = tmp[t];
    if (t == 1023) blk[blockIdx.x] = tmp[t];
}

__global__ void scan2_kernel(int* __restrict__ blk, int nb) {
    if (blockIdx.x == 0 && threadIdx.x == 0) {
        int run = 0;
        for (int i = 0; i < nb; i++) { int t = blk[i]; blk[i] = run; run += t; }
    }
}

__global__ void scan3_kernel(int* __restrict__ row_ptr, const int* __restrict__ blk) {
    int n = blockIdx.x * blockDim.x + threadIdx.x;
    if (n < N_NODES) row_ptr[n + 1] += blk[n >> 10];
    if (n == 0) row_ptr[0] = 0;
}

__global__ void fillcopy_kernel(const int* __restrict__ row_ptr, int* __restrict__ fill) {
    int n = blockIdx.x * blockDim.x + threadIdx.x;
    if (n < N_NODES) fill[n] = row_ptr[n];
}

__global__ void scatter_kernel(const int* __restrict__ src, const int* __restrict__ dst,
                               int* __restrict__ fill,
                               int* __restrict__ perm, int* __restrict__ srcP) {
    int e = blockIdx.x * blockDim.x + threadIdx.x;
    if (e < N_EDGES) {
        int pos = atomicAdd(&fill[dst[e]], 1);
        perm[pos] = e;
        srcP[pos] = src[e];
    }
}

// ---------------- node transform: persistent weight columns in VGPRs ----------------
// lane k holds column k of Wl and Wr in registers; h broadcast via v_readlane.

template <int K>
__global__ __launch_bounds__(256, 2) void transform2_kernel(
    const float* __restrict__ h,
    const float* __restrict__ Wl, const float* __restrict__ bl,
    const float* __restrict__ Wr, const float* __restrict__ br,
    float* __restrict__ xl, float* __restrict__ xr) {
    int t = threadIdx.x;
    int w = t >> 6;
    int k = t & 63;
    float wl[K], wr[K];
#pragma unroll
    for (int j = 0; j < K; j++) { wl[j] = Wl[j * 64 + k]; wr[j] = Wr[j * 64 + k]; }
    float blk = bl[k], brk = br[k];
    int wid = blockIdx.x * 4 + w;
    const int NW = gridDim.x * 4;
    for (int n = wid; n < N_NODES; n += NW) {
        float hv = (k < K) ? h[n * K + k] : 0.f;
        float al = blk, ar = brk;
#pragma unroll
        for (int j = 0; j < K; j++) {
            float hj = __int_as_float(__builtin_amdgcn_readlane(__float_as_int(hv), j));
            al = fmaf(hj, wl[j], al);
            ar = fmaf(hj, wr[j], ar);
        }
        xl[n * 64 + k] = al;
        xr[n * 64 + k] = ar;
    }
}

// ---------------- pass A: edge-parallel logits (16 lanes per edge, float4) ----------------

__global__ __launch_bounds__(256) void logit_kernel(
    const float* __restrict__ xl, const float* __restrict__ xr,
    const float* __restrict__ ea,
    const int* __restrict__ src, const int* __restrict__ dst,
    const float* __restrict__ We, const float* __restrict__ att,
    float* __restrict__ logit) {
    int t = threadIdx.x;
    int li = t & 15;
    int grp = t >> 4;
    int e = blockIdx.x * 16 + grp;   // grid exact: 800000 = 50000*16
    int k4 = li * 4;
    float4 we0 = *(const float4*)(We + 0 * 64 + k4);
    float4 we1 = *(const float4*)(We + 1 * 64 + k4);
    float4 we2 = *(const float4*)(We + 2 * 64 + k4);
    float4 at  = *(const float4*)(att + k4);
    int s = src[e], d = dst[e];
    float e0 = ea[e * 3 + 0], e1 = ea[e * 3 + 1], e2 = ea[e * 3 + 2];
    float4 a = *(const float4*)(xl + (size_t)s * 64 + k4);
    float4 b = *(const float4*)(xr + (size_t)d * 64 + k4);
    float acc;
    {
        float tt = a.x + b.x + e0 * we0.x + e1 * we1.x + e2 * we2.x;
        tt = (tt > 0.f) ? tt : SLOPE * tt;
        acc = at.x * tt;
    }
    {
        float tt = a.y + b.y + e0 * we0.y + e1 * we1.y + e2 * we2.y;
        tt = (tt > 0.f) ? tt : SLOPE * tt;
        acc = fmaf(at.y, tt, acc);
    }
    {
        float tt = a.z + b.z + e0 * we0.z + e1 * we1.z + e2 * we2.z;
        tt = (tt > 0.f) ? tt : SLOPE * tt;
        acc = fmaf(at.z, tt, acc);
    }
    {
        float tt = a.w + b.w + e0 * we0.w + e1 * we1.w + e2 * we2.w;
        tt = (tt > 0.f) ? tt : SLOPE * tt;
        acc = fmaf(at.w, tt, acc);
    }
    for (int off = 8; off > 0; off >>= 1) acc += __shfl_xor(acc, off, 64);
    if (li == 0) logit[e] = acc;
}

// ---------------- pass B: wave-per-node aggregation (lane-parallel softmax) ----------------

__global__ __launch_bounds__(256) void aggregate_kernel(
    const float* __restrict__ xl,
    const float* __restrict__ logit,
    const int* __restrict__ perm, const int* __restrict__ srcP,
    const int* __restrict__ row_ptr,
    const float* __restrict__ bo,
    const float* __restrict__ bn_g, const float* __restrict__ bn_b,
    const float* __restrict__ bn_m, const float* __restrict__ bn_v,
    float* __restrict__ hout) {
    __shared__ float sp[4][64];
    __shared__ int   ss[4][64];
    int t = threadIdx.x;
    int w = t >> 6;
    int k = t & 63;
    int n = blockIdx.x * 4 + w;   // grid exact: 12500*4
    int beg = row_ptr[n], end = row_ptr[n + 1];

    float m = -INFINITY, z = 0.f, o = 0.f;
    for (int c = beg; c < end; c += 64) {
        int cnt = min(end - c, 64);
        float lv = -INFINITY;
        int s = 0;
        if (k < cnt) {
            int e = perm[c + k];
            lv = logit[e];
            s = srcP[c + k];
        }
        float mc = lv;
        for (int off = 32; off > 0; off >>= 1) mc = fmaxf(mc, __shfl_xor(mc, off, 64));
        float mn = fmaxf(m, mc);
        float scale = expf(m - mn);   // first chunk: expf(-inf)=0
        float p = (k < cnt) ? expf(lv - mn) : 0.f;
        float zc = p;
        for (int off = 32; off > 0; off >>= 1) zc += __shfl_xor(zc, off, 64);
        z = z * scale + zc;
        o = o * scale;
        sp[w][k] = p;
        ss[w][k] = s;
        for (int j = 0; j < cnt; j++) {
            float pj = sp[w][j];
            int sj = ss[w][j];
            o = fmaf(pj, xl[(size_t)sj * 64 + k], o);
        }
        m = mn;
    }
    float outv = o / fmaxf(z, 1e-16f) + bo[k];
    float inv = 1.0f / sqrtf(bn_v[k] + EPS_BN);
    float hn = (outv - bn_m[k]) * (bn_g[k] * inv) + bn_b[k];
    hout[n * 64 + k] = fmaxf(hn, 0.f);
}

// ---------------- readout ----------------

__global__ void bounds_kernel(const int* __restrict__ batch, int* __restrict__ gstart) {
    int g = blockIdx.x * blockDim.x + threadIdx.x;
    if (g > N_GRAPHS) return;
    int lo = 0, hi = N_NODES;
    while (lo < hi) {
        int mid = (lo + hi) >> 1;
        if (batch[mid] < g) lo = mid + 1; else hi = mid;
    }
    gstart[g] = lo;
}

__global__ void wcomb_kernel(const float* __restrict__ Wjk, const float* __restrict__ bjk,
                             const float* __restrict__ Whead, const float* __restrict__ bhead,
                             float* __restrict__ wcomb, float* __restrict__ bcomb) {
    int k = threadIdx.x;
    if (k < 64) {
        float s = 0.f;
        for (int j = 0; j < 64; j++) s += Wjk[k * 64 + j] * Whead[j];
        wcomb[k] = s;
    }
    if (k == 0) {
        float s = 0.f;
        for (int j = 0; j < 64; j++) s += bjk[j] * Whead[j];
        *bcomb = s + bhead[0];
    }
}

__global__ __launch_bounds__(64) void pool_kernel(
    const float* __restrict__ h, const int* __restrict__ gstart,
    const float* __restrict__ wcomb, const float* __restrict__ bcomb,
    float* __restrict__ out) {
    int g = blockIdx.x;
    int k = threadIdx.x;
    int s = gstart[g], e = gstart[g + 1];
    float acc = 0.f;
    for (int n = s; n < e; ++n) acc += h[n * 64 + k];
    float cnt = (float)(e - s);
    acc /= fmaxf(cnt, 1.0f);
    float v = acc * wcomb[k];
    for (int off = 32; off > 0; off >>= 1) v += __shfl_xor(v, off, 64);
    if (k == 0) out[g] = v + *bcomb;
}

// ---------------- launch ----------------

extern "C" void kernel_launch(void* const* d_in, const int* in_sizes, int n_in,
                              void* d_out, int out_size, void* d_ws, size_t ws_size,
                              hipStream_t stream) {
    const float* x     = (const float*)d_in[0];
    const float* ea    = (const float*)d_in[1];
    const float* Wl0   = (const float*)d_in[2];
    const float* Wr0   = (const float*)d_in[3];
    const float* bl0   = (const float*)d_in[4];
    const float* br0   = (const float*)d_in[5];
    const float* We0   = (const float*)d_in[6];
    const float* att0  = (const float*)d_in[7];
    const float* bo0   = (const float*)d_in[8];
    const float* Wl    = (const float*)d_in[9];
    const float* Wr    = (const float*)d_in[10];
    const float* bl    = (const float*)d_in[11];
    const float* br    = (const float*)d_in[12];
    const float* We    = (const float*)d_in[13];
    const float* att   = (const float*)d_in[14];
    const float* bo    = (const float*)d_in[15];
    const float* bn_g  = (const float*)d_in[16];
    const float* bn_b  = (const float*)d_in[17];
    const float* bn_m  = (const float*)d_in[18];
    const float* bn_v  = (const float*)d_in[19];
    const float* Wjk   = (const float*)d_in[20];
    const float* bjk   = (const float*)d_in[21];
    const float* Whead = (const float*)d_in[22];
    const float* bhead = (const float*)d_in[23];
    const int* edge_index = (const int*)d_in[24];
    const int* batch      = (const int*)d_in[25];

    const int* srcIdx = edge_index;            // edge_index[0]
    const int* dstIdx = edge_index + N_EDGES;  // edge_index[1]

    char* ws = (char*)d_ws;
    size_t off = 0;
    auto alloc = [&](size_t bytes) -> void* {
        void* p = ws + off;
        off += (bytes + 255) & ~(size_t)255;
        return p;
    };
    float* hA      = (float*)alloc((size_t)N_NODES * 64 * 4);
    float* hB      = (float*)alloc((size_t)N_NODES * 64 * 4);
    float* xlb     = (float*)alloc((size_t)N_NODES * 64 * 4);
    float* xrb     = (float*)alloc((size_t)N_NODES * 64 * 4);
    int*   row_ptr = (int*)alloc((size_t)(N_NODES + 1) * 4);
    int*   fill    = (int*)alloc((size_t)N_NODES * 4);
    int*   blk     = (int*)alloc(64 * 4);
    int*   perm    = (int*)alloc((size_t)N_EDGES * 4);
    int*   srcP    = (int*)alloc((size_t)N_EDGES * 4);
    float* logitB  = (float*)alloc((size_t)N_EDGES * 4);
    int*   gstart  = (int*)alloc((size_t)(N_GRAPHS + 1) * 4);
    float* wcomb   = (float*)alloc(64 * 4);
    float* bcomb   = (float*)alloc(4);

    // ---- CSR build (sort edges by dst) ----
    hipMemsetAsync(fill, 0, (size_t)N_NODES * 4, stream);
    hist_kernel<<<(N_EDGES + 255) / 256, 256, 0, stream>>>(dstIdx, fill);
    const int SCB = (N_NODES + 1023) / 1024;  // 49
    scan1_kernel<<<SCB, 1024, 0, stream>>>(fill, row_ptr, blk);
    scan2_kernel<<<1, 1, 0, stream>>>(blk, SCB);
    scan3_kernel<<<(N_NODES + 255) / 256, 256, 0, stream>>>(row_ptr, blk);
    fillcopy_kernel<<<(N_NODES + 255) / 256, 256, 0, stream>>>(row_ptr, fill);
    scatter_kernel<<<(N_EDGES + 255) / 256, 256, 0, stream>>>(srcIdx, dstIdx, fill, perm, srcP);

    const int NBN = N_NODES / 4;   // 12500 (aggregate grid)
    const int NBE = N_EDGES / 16;  // 50000 (logit grid)
    const int NBT = 512;           // transform grid (persistent)

    // ---- layer 0 (input dim 9) ----
    transform2_kernel<9><<<NBT, 256, 0, stream>>>(x, Wl0, bl0, Wr0, br0, xlb, xrb);
    logit_kernel<<<NBE, 256, 0, stream>>>(xlb, xrb, ea, srcIdx, dstIdx, We0, att0, logitB);
    aggregate_kernel<<<NBN, 256, 0, stream>>>(xlb, logitB, perm, srcP, row_ptr,
                                              bo0, bn_g, bn_b, bn_m, bn_v, hA);

    // ---- layers 1..4 ----
    float* hcur = hA;
    float* hnext = hB;
    for (int i = 0; i < 4; i++) {
        transform2_kernel<64><<<NBT, 256, 0, stream>>>(hcur,
            Wl + (size_t)i * 64 * 64, bl + (size_t)i * 64,
            Wr + (size_t)i * 64 * 64, br + (size_t)i * 64,
            xlb, xrb);
        logit_kernel<<<NBE, 256, 0, stream>>>(xlb, xrb, ea, srcIdx, dstIdx,
                                              We + (size_t)i * 3 * 64, att + (size_t)i * 64, logitB);
        aggregate_kernel<<<NBN, 256, 0, stream>>>(xlb, logitB, perm, srcP, row_ptr,
            bo + (size_t)i * 64,
            bn_g + (size_t)(i + 1) * 64, bn_b + (size_t)(i + 1) * 64,
            bn_m + (size_t)(i + 1) * 64, bn_v + (size_t)(i + 1) * 64,
            hnext);
        float* tp = hcur; hcur = hnext; hnext = tp;
    }

    // ---- readout ----
    bounds_kernel<<<3, 256, 0, stream>>>(batch, gstart);
    wcomb_kernel<<<1, 64, 0, stream>>>(Wjk, bjk, Whead, bhead, wcomb, bcomb);
    pool_kernel<<<N_GRAPHS, 64, 0, stream>>>(hcur, gstart, wcomb, bcomb, (float*)d_out);
}

// Round 3
// 807.919 us; speedup vs baseline: 1.4972x; 1.0734x over previous
//
#include <hip/hip_runtime.h>
#include <math.h>

#define N_NODES 50000
#define N_EDGES 800000
#define N_GRAPHS 512
#define SLOPE 0.2f
static constexpr float EPS_BN = 1e-5f;

// ---------------- CSR build ----------------

__global__ void hist_kernel(const int* __restrict__ dst, int* __restrict__ cnt) {
    int e = blockIdx.x * blockDim.x + threadIdx.x;
    if (e < N_EDGES) atomicAdd(&cnt[dst[e]], 1);
}

__global__ void scan1_kernel(const int* __restrict__ cnt, int* __restrict__ row_ptr,
                             int* __restrict__ blk) {
    __shared__ int tmp[1024];
    int t = threadIdx.x;
    int n = blockIdx.x * 1024 + t;
    int v = (n < N_NODES) ? cnt[n] : 0;
    tmp[t] = v;
    __syncthreads();
    for (int off = 1; off < 1024; off <<= 1) {
        int x = (t >= off) ? tmp[t - off] : 0;
        __syncthreads();
        tmp[t] += x;
        __syncthreads();
    }
    if (n < N_NODES) row_ptr[n + 1] = tmp[t];
    if (t == 1023) blk[blockIdx.x] = tmp[t];
}

__global__ void scan2_kernel(int* __restrict__ blk, int nb) {
    if (blockIdx.x == 0 && threadIdx.x == 0) {
        int run = 0;
        for (int i = 0; i < nb; i++) { int t = blk[i]; blk[i] = run; run += t; }
    }
}

__global__ void scan3_kernel(int* __restrict__ row_ptr, const int* __restrict__ blk) {
    int n = blockIdx.x * blockDim.x + threadIdx.x;
    if (n < N_NODES) row_ptr[n + 1] += blk[n >> 10];
    if (n == 0) row_ptr[0] = 0;
}

__global__ void fillcopy_kernel(const int* __restrict__ row_ptr, int* __restrict__ fill) {
    int n = blockIdx.x * blockDim.x + threadIdx.x;
    if (n < N_NODES) fill[n] = row_ptr[n];
}

__global__ void scatter_kernel(const int* __restrict__ src, const int* __restrict__ dst,
                               int* __restrict__ fill,
                               int* __restrict__ perm, int* __restrict__ srcP) {
    int e = blockIdx.x * blockDim.x + threadIdx.x;
    if (e < N_EDGES) {
        int pos = atomicAdd(&fill[dst[e]], 1);
        perm[pos] = e;
        srcP[pos] = src[e];
    }
}

// permute edge attrs into CSR order, padded to float4 for clean vector loads
__global__ void permute_ea_kernel(const int* __restrict__ perm, const float* __restrict__ ea,
                                  float4* __restrict__ eaP4) {
    int p = blockIdx.x * blockDim.x + threadIdx.x;
    if (p < N_EDGES) {
        int e = perm[p];
        eaP4[p] = make_float4(ea[e * 3 + 0], ea[e * 3 + 1], ea[e * 3 + 2], 0.f);
    }
}

// dstP[p] = n for p in [row_ptr[n], row_ptr[n+1])  -- no gather needed
__global__ void fill_dstP_kernel(const int* __restrict__ row_ptr, int* __restrict__ dstP) {
    int n = blockIdx.x * blockDim.x + threadIdx.x;
    if (n < N_NODES) {
        int b = row_ptr[n], e = row_ptr[n + 1];
        for (int p = b; p < e; ++p) dstP[p] = n;
    }
}

// ---------------- node transform: persistent weight columns in VGPRs ----------------

template <int K>
__global__ __launch_bounds__(256, 2) void transform2_kernel(
    const float* __restrict__ h,
    const float* __restrict__ Wl, const float* __restrict__ bl,
    const float* __restrict__ Wr, const float* __restrict__ br,
    float* __restrict__ xl, float* __restrict__ xr) {
    int t = threadIdx.x;
    int w = t >> 6;
    int k = t & 63;
    float wl[K], wr[K];
#pragma unroll
    for (int j = 0; j < K; j++) { wl[j] = Wl[j * 64 + k]; wr[j] = Wr[j * 64 + k]; }
    float blk = bl[k], brk = br[k];
    int wid = blockIdx.x * 4 + w;
    const int NW = gridDim.x * 4;
    for (int n = wid; n < N_NODES; n += NW) {
        float hv = (k < K) ? h[n * K + k] : 0.f;
        float al = blk, ar = brk;
#pragma unroll
        for (int j = 0; j < K; j++) {
            float hj = __int_as_float(__builtin_amdgcn_readlane(__float_as_int(hv), j));
            al = fmaf(hj, wl[j], al);
            ar = fmaf(hj, wr[j], ar);
        }
        xl[n * 64 + k] = al;
        xr[n * 64 + k] = ar;
    }
}

// ---------------- pass A: position-ordered logits (16 lanes per edge, float4) ----------------

__global__ __launch_bounds__(256) void logit_kernel(
    const float* __restrict__ xl, const float* __restrict__ xr,
    const float4* __restrict__ eaP4,
    const int* __restrict__ srcP, const int* __restrict__ dstP,
    const float* __restrict__ We, const float* __restrict__ att,
    float* __restrict__ logitP) {
    int t = threadIdx.x;
    int li = t & 15;
    int grp = t >> 4;
    int p = blockIdx.x * 16 + grp;   // grid exact: 800000 = 50000*16
    int k4 = li * 4;
    float4 we0 = *(const float4*)(We + 0 * 64 + k4);
    float4 we1 = *(const float4*)(We + 1 * 64 + k4);
    float4 we2 = *(const float4*)(We + 2 * 64 + k4);
    float4 at  = *(const float4*)(att + k4);
    int s = srcP[p], d = dstP[p];
    float4 ev = eaP4[p];
    float4 a = *(const float4*)(xl + (size_t)s * 64 + k4);
    float4 b = *(const float4*)(xr + (size_t)d * 64 + k4);
    float acc;
    {
        float tt = a.x + b.x + ev.x * we0.x + ev.y * we1.x + ev.z * we2.x;
        tt = (tt > 0.f) ? tt : SLOPE * tt;
        acc = at.x * tt;
    }
    {
        float tt = a.y + b.y + ev.x * we0.y + ev.y * we1.y + ev.z * we2.y;
        tt = (tt > 0.f) ? tt : SLOPE * tt;
        acc = fmaf(at.y, tt, acc);
    }
    {
        float tt = a.z + b.z + ev.x * we0.z + ev.y * we1.z + ev.z * we2.z;
        tt = (tt > 0.f) ? tt : SLOPE * tt;
        acc = fmaf(at.z, tt, acc);
    }
    {
        float tt = a.w + b.w + ev.x * we0.w + ev.y * we1.w + ev.z * we2.w;
        tt = (tt > 0.f) ? tt : SLOPE * tt;
        acc = fmaf(at.w, tt, acc);
    }
    for (int off = 8; off > 0; off >>= 1) acc += __shfl_xor(acc, off, 64);
    if (li == 0) logitP[p] = acc;
}

// ---------------- pass B: wave-per-node aggregation (lane-parallel softmax) ----------------

__global__ __launch_bounds__(256) void aggregate_kernel(
    const float* __restrict__ xl,
    const float* __restrict__ logitP,
    const int* __restrict__ srcP,
    const int* __restrict__ row_ptr,
    const float* __restrict__ bo,
    const float* __restrict__ bn_g, const float* __restrict__ bn_b,
    const float* __restrict__ bn_m, const float* __restrict__ bn_v,
    float* __restrict__ hout) {
    __shared__ float sp[4][64];
    __shared__ int   ss[4][64];
    int t = threadIdx.x;
    int w = t >> 6;
    int k = t & 63;
    int n = blockIdx.x * 4 + w;   // grid exact: 12500*4
    int beg = row_ptr[n], end = row_ptr[n + 1];

    float m = -INFINITY, z = 0.f, o = 0.f;
    for (int c = beg; c < end; c += 64) {
        int cnt = min(end - c, 64);
        float lv = -INFINITY;
        int s = 0;
        if (k < cnt) {
            lv = logitP[c + k];
            s = srcP[c + k];
        }
        float mc = lv;
        for (int off = 32; off > 0; off >>= 1) mc = fmaxf(mc, __shfl_xor(mc, off, 64));
        float mn = fmaxf(m, mc);
        float scale = expf(m - mn);   // first chunk: expf(-inf)=0
        float p = (k < cnt) ? expf(lv - mn) : 0.f;
        float zc = p;
        for (int off = 32; off > 0; off >>= 1) zc += __shfl_xor(zc, off, 64);
        z = z * scale + zc;
        o = o * scale;
        sp[w][k] = p;
        ss[w][k] = s;
        for (int j = 0; j < cnt; j++) {
            float pj = sp[w][j];
            int sj = ss[w][j];
            o = fmaf(pj, xl[(size_t)sj * 64 + k], o);
        }
        m = mn;
    }
    float outv = o / fmaxf(z, 1e-16f) + bo[k];
    float inv = 1.0f / sqrtf(bn_v[k] + EPS_BN);
    float hn = (outv - bn_m[k]) * (bn_g[k] * inv) + bn_b[k];
    hout[n * 64 + k] = fmaxf(hn, 0.f);
}

// ---------------- readout ----------------

__global__ void bounds_kernel(const int* __restrict__ batch, int* __restrict__ gstart) {
    int g = blockIdx.x * blockDim.x + threadIdx.x;
    if (g > N_GRAPHS) return;
    int lo = 0, hi = N_NODES;
    while (lo < hi) {
        int mid = (lo + hi) >> 1;
        if (batch[mid] < g) lo = mid + 1; else hi = mid;
    }
    gstart[g] = lo;
}

__global__ void wcomb_kernel(const float* __restrict__ Wjk, const float* __restrict__ bjk,
                             const float* __restrict__ Whead, const float* __restrict__ bhead,
                             float* __restrict__ wcomb, float* __restrict__ bcomb) {
    int k = threadIdx.x;
    if (k < 64) {
        float s = 0.f;
        for (int j = 0; j < 64; j++) s += Wjk[k * 64 + j] * Whead[j];
        wcomb[k] = s;
    }
    if (k == 0) {
        float s = 0.f;
        for (int j = 0; j < 64; j++) s += bjk[j] * Whead[j];
        *bcomb = s + bhead[0];
    }
}

__global__ __launch_bounds__(64) void pool_kernel(
    const float* __restrict__ h, const int* __restrict__ gstart,
    const float* __restrict__ wcomb, const float* __restrict__ bcomb,
    float* __restrict__ out) {
    int g = blockIdx.x;
    int k = threadIdx.x;
    int s = gstart[g], e = gstart[g + 1];
    float acc = 0.f;
    for (int n = s; n < e; ++n) acc += h[n * 64 + k];
    float cnt = (float)(e - s);
    acc /= fmaxf(cnt, 1.0f);
    float v = acc * wcomb[k];
    for (int off = 32; off > 0; off >>= 1) v += __shfl_xor(v, off, 64);
    if (k == 0) out[g] = v + *bcomb;
}

// ---------------- launch ----------------

extern "C" void kernel_launch(void* const* d_in, const int* in_sizes, int n_in,
                              void* d_out, int out_size, void* d_ws, size_t ws_size,
                              hipStream_t stream) {
    const float* x     = (const float*)d_in[0];
    const float* ea    = (const float*)d_in[1];
    const float* Wl0   = (const float*)d_in[2];
    const float* Wr0   = (const float*)d_in[3];
    const float* bl0   = (const float*)d_in[4];
    const float* br0   = (const float*)d_in[5];
    const float* We0   = (const float*)d_in[6];
    const float* att0  = (const float*)d_in[7];
    const float* bo0   = (const float*)d_in[8];
    const float* Wl    = (const float*)d_in[9];
    const float* Wr    = (const float*)d_in[10];
    const float* bl    = (const float*)d_in[11];
    const float* br    = (const float*)d_in[12];
    const float* We    = (const float*)d_in[13];
    const float* att   = (const float*)d_in[14];
    const float* bo    = (const float*)d_in[15];
    const float* bn_g  = (const float*)d_in[16];
    const float* bn_b  = (const float*)d_in[17];
    const float* bn_m  = (const float*)d_in[18];
    const float* bn_v  = (const float*)d_in[19];
    const float* Wjk   = (const float*)d_in[20];
    const float* bjk   = (const float*)d_in[21];
    const float* Whead = (const float*)d_in[22];
    const float* bhead = (const float*)d_in[23];
    const int* edge_index = (const int*)d_in[24];
    const int* batch      = (const int*)d_in[25];

    const int* srcIdx = edge_index;            // edge_index[0]
    const int* dstIdx = edge_index + N_EDGES;  // edge_index[1]

    char* ws = (char*)d_ws;
    size_t off = 0;
    auto alloc = [&](size_t bytes) -> void* {
        void* p = ws + off;
        off += (bytes + 255) & ~(size_t)255;
        return p;
    };
    float* hA      = (float*)alloc((size_t)N_NODES * 64 * 4);
    float* hB      = (float*)alloc((size_t)N_NODES * 64 * 4);
    float* xlb     = (float*)alloc((size_t)N_NODES * 64 * 4);
    float* xrb     = (float*)alloc((size_t)N_NODES * 64 * 4);
    int*   row_ptr = (int*)alloc((size_t)(N_NODES + 1) * 4);
    int*   fill    = (int*)alloc((size_t)N_NODES * 4);
    int*   blk     = (int*)alloc(64 * 4);
    int*   perm    = (int*)alloc((size_t)N_EDGES * 4);
    int*   srcP    = (int*)alloc((size_t)N_EDGES * 4);
    int*   dstP    = (int*)alloc((size_t)N_EDGES * 4);
    float4* eaP4   = (float4*)alloc((size_t)N_EDGES * 16);
    float* logitB  = (float*)alloc((size_t)N_EDGES * 4);
    int*   gstart  = (int*)alloc((size_t)(N_GRAPHS + 1) * 4);
    float* wcomb   = (float*)alloc(64 * 4);
    float* bcomb   = (float*)alloc(4);

    // ---- CSR build (sort edges by dst) ----
    hipMemsetAsync(fill, 0, (size_t)N_NODES * 4, stream);
    hist_kernel<<<(N_EDGES + 255) / 256, 256, 0, stream>>>(dstIdx, fill);
    const int SCB = (N_NODES + 1023) / 1024;  // 49
    scan1_kernel<<<SCB, 1024, 0, stream>>>(fill, row_ptr, blk);
    scan2_kernel<<<1, 1, 0, stream>>>(blk, SCB);
    scan3_kernel<<<(N_NODES + 255) / 256, 256, 0, stream>>>(row_ptr, blk);
    fillcopy_kernel<<<(N_NODES + 255) / 256, 256, 0, stream>>>(row_ptr, fill);
    scatter_kernel<<<(N_EDGES + 255) / 256, 256, 0, stream>>>(srcIdx, dstIdx, fill, perm, srcP);
    permute_ea_kernel<<<(N_EDGES + 255) / 256, 256, 0, stream>>>(perm, ea, eaP4);
    fill_dstP_kernel<<<(N_NODES + 255) / 256, 256, 0, stream>>>(row_ptr, dstP);

    const int NBN = N_NODES / 4;   // 12500 (aggregate grid)
    const int NBE = N_EDGES / 16;  // 50000 (logit grid)
    const int NBT = 512;           // transform grid (persistent)

    // ---- layer 0 (input dim 9) ----
    transform2_kernel<9><<<NBT, 256, 0, stream>>>(x, Wl0, bl0, Wr0, br0, xlb, xrb);
    logit_kernel<<<NBE, 256, 0, stream>>>(xlb, xrb, eaP4, srcP, dstP, We0, att0, logitB);
    aggregate_kernel<<<NBN, 256, 0, stream>>>(xlb, logitB, srcP, row_ptr,
                                              bo0, bn_g, bn_b, bn_m, bn_v, hA);

    // ---- layers 1..4 ----
    float* hcur = hA;
    float* hnext = hB;
    for (int i = 0; i < 4; i++) {
        transform2_kernel<64><<<NBT, 256, 0, stream>>>(hcur,
            Wl + (size_t)i * 64 * 64, bl + (size_t)i * 64,
            Wr + (size_t)i * 64 * 64, br + (size_t)i * 64,
            xlb, xrb);
        logit_kernel<<<NBE, 256, 0, stream>>>(xlb, xrb, eaP4, srcP, dstP,
                                              We + (size_t)i * 3 * 64, att + (size_t)i * 64, logitB);
        aggregate_kernel<<<NBN, 256, 0, stream>>>(xlb, logitB, srcP, row_ptr,
            bo + (size_t)i * 64,
            bn_g + (size_t)(i + 1) * 64, bn_b + (size_t)(i + 1) * 64,
            bn_m + (size_t)(i + 1) * 64, bn_v + (size_t)(i + 1) * 64,
            hnext);
        float* tp = hcur; hcur = hnext; hnext = tp;
    }

    // ---- readout ----
    bounds_kernel<<<3, 256, 0, stream>>>(batch, gstart);
    wcomb_kernel<<<1, 64, 0, stream>>>(Wjk, bjk, Whead, bhead, wcomb, bcomb);
    pool_kernel<<<N_GRAPHS, 64, 0, stream>>>(hcur, gstart, wcomb, bcomb, (float*)d_out);
}